// Round 5
// baseline (153.717 us; speedup 1.0000x reference)
//
#include <hip/hip_runtime.h>
#include <hip/hip_bf16.h>

#define RANK 16
#define BATCH 32768
#define K_DIM 4096   // A1*B1
#define N_DIM 64     // A2*B2
#define CHUNK 64     // K floats per staged chunk (256B per row)
#define NCHUNK 64    // 4096/64
#define NBUF 3
#define ROWB 64      // rows per block

typedef __bf16 bf16x8 __attribute__((ext_vector_type(8)));
typedef float f32x16 __attribute__((ext_vector_type(16)));
typedef unsigned short ushort8 __attribute__((ext_vector_type(8)));

#define WAITVM(n) asm volatile("s_waitcnt vmcnt(" #n ")" ::: "memory")
#define BARRIER() asm volatile("s_barrier" ::: "memory")

__device__ inline unsigned short f2bf(float f) {
  unsigned u = __builtin_bit_cast(unsigned, f);
  u += 0x7fffu + ((u >> 16) & 1u);   // round-to-nearest-even
  return (unsigned short)(u >> 16);
}

__device__ inline bf16x8 cvt8(float4 a0, float4 a1) {
  ushort8 au;
  au[0] = f2bf(a0.x); au[1] = f2bf(a0.y); au[2] = f2bf(a0.z); au[3] = f2bf(a0.w);
  au[4] = f2bf(a1.x); au[5] = f2bf(a1.y); au[6] = f2bf(a1.z); au[7] = f2bf(a1.w);
  return __builtin_bit_cast(bf16x8, au);
}

// Fragment-major packed weights for mfma_f32_32x32x16_bf16 B-operand:
// wF[((cb*256 + t)*64 + lane)*8 + j] = w[k][n],
//   n = cb*32 + (lane&31), k = t*16 + (lane>>5)*8 + j.
// Every 1KB-aligned 64-lane slice is one wave's B-fragment, so both the
// gll staging load and the ds_read are fully dense.
__global__ __launch_bounds__(256) void build_wF(
    const float* __restrict__ s, const float* __restrict__ a,
    const float* __restrict__ b, unsigned short* __restrict__ wF) {
  int e = blockIdx.x * 256 + threadIdx.x;          // 0 .. 262143
  int j  = e & 7;
  int l  = (e >> 3) & 63;
  int t  = (e >> 9) & 255;
  int cb = e >> 17;
  int n = cb * 32 + (l & 31);
  int k = t * 16 + ((l >> 5) << 3) + j;
  int i = k >> 6, kk = k & 63, jj = n >> 3, ll = n & 7;
  float acc = 0.f;
  #pragma unroll
  for (int r = 0; r < RANK; ++r) {
    acc += a[r * 512 + i * 8 + jj] * b[r * 512 + kk * 8 + ll];
  }
  acc *= s[i * 8 + jj];
  wF[e] = f2bf(acc);
}

// Block = 64 rows x 64 cols, 4 waves = 2x2 quadrants of 32x32 (one
// mfma_f32_32x32x16_bf16 acc each). x AND w staged to LDS with
// global_load_lds (contiguous 1KB instrs); compute phase issues ONLY
// ds_reads (lgkmcnt) so the counted vmcnt(12) ring (3 bufs, depth-2
// prefetch, raw s_barrier — never vmcnt(0) in the main loop) keeps two
// chunk-stages in flight across barriers. A-tile XOR-swizzled
// (unit ^= row&15, applied on global source AND on ds_read) -> even
// bank spread for the 32-consecutive-row b128 reads.
__global__ __launch_bounds__(256, 2) void kron_gemm(
    const float* __restrict__ x, const unsigned short* __restrict__ wF,
    const float* __restrict__ bias, float* __restrict__ out) {
  __shared__ __align__(16) float  As[NBUF][ROWB * CHUNK];   // 3 x 16KB
  __shared__ __align__(16) __bf16 Ws[NBUF][8][64 * 8];      // 3 x 8KB

  const int tid  = threadIdx.x;
  const int lane = tid & 63;
  const int wave = tid >> 6;
  const int qr   = wave & 1;          // row quadrant
  const int qc   = wave >> 1;         // col quadrant
  const int l31  = lane & 31;
  const int hi   = lane >> 5;
  const int m0   = blockIdx.x * ROWB;
  const int arow = qr * 32 + l31;              // my A row in the tile
  const int aswz = (arow & 15) << 4;           // read-side swizzle XOR

  f32x16 acc;
  #pragma unroll
  for (int i = 0; i < 16; ++i) acc[i] = 0.f;

  // stage chunk c into buffer buf: 4 A-instrs + 2 W-instrs per wave
  auto stage = [&](int buf, int c) {
    #pragma unroll
    for (int p = 0; p < 4; ++p) {
      const int rbase = wave * 16 + 4 * p;           // wave-uniform
      const int row   = rbase + (lane >> 4);         // per-lane
      const int sb    = (((lane & 15) ^ (row & 15)) << 4);
      const float* src = x + (size_t)(m0 + row) * K_DIM + c * CHUNK + (sb >> 2);
      float* dst = &As[buf][rbase * CHUNK];
      __builtin_amdgcn_global_load_lds(
          (const __attribute__((address_space(1))) void*)(const void*)src,
          (__attribute__((address_space(3))) void*)(void*)dst, 16, 0, 0);
    }
    #pragma unroll
    for (int p = 0; p < 2; ++p) {
      const int idx = wave * 2 + p;                  // 0..7
      const int r = idx >> 2, sub = idx & 3;
      const unsigned short* src =
          wF + (((size_t)(r * 256 + c * 4 + sub)) << 9) + lane * 8;
      __bf16* dst = &Ws[buf][r * 4 + sub][0];
      __builtin_amdgcn_global_load_lds(
          (const __attribute__((address_space(1))) void*)(const void*)src,
          (__attribute__((address_space(3))) void*)(void*)dst, 16, 0, 0);
    }
  };

  // compute chunk in buffer buf: pure LDS reads + MFMA, no vmem
  auto compute = [&](int buf) {
    const char* Ab = (const char*)&As[buf][0];
    #pragma unroll
    for (int t = 0; t < 4; ++t) {
      bf16x8 wf = *(const bf16x8*)&Ws[buf][qc * 4 + t][lane * 8];
      const int colb = t * 64 + hi * 32;
      float4 lo = *(const float4*)(Ab + arow * 256 + ((colb)      ^ aswz));
      float4 h4 = *(const float4*)(Ab + arow * 256 + ((colb + 16) ^ aswz));
      acc = __builtin_amdgcn_mfma_f32_32x32x16_bf16(cvt8(lo, h4), wf, acc, 0, 0, 0);
    }
  };

  // ---- prologue: stages 0,1 in flight ----
  stage(0, 0);
  stage(1, 1);

  int b0 = 0, b1 = 1, b2 = 2;   // buffers of chunks c, c+1, c+2
  for (int c = 0; c < NCHUNK - 2; ++c) {
    stage(b2, c + 2);     // writes buf of chunk c-1; safe: end-of-prev-iter barrier
    WAITVM(12);           // my stage(c) landed (c+1,c+2 = 12 newer ops stay in flight)
    BARRIER();            // everyone's stage(c) landed
    compute(b0);
    BARRIER();            // all waves done reading buf b0 -> next iter may overwrite
    const int tmp = b0; b0 = b1; b1 = b2; b2 = tmp;
  }
  // ---- tail: chunks 62, 63 ----
  WAITVM(6);  BARRIER(); compute(b0);
  WAITVM(0);  BARRIER(); compute(b1);

  // ---- epilogue: C/D 32x32 mapping col=lane&31, row=(r&3)+8*(r>>2)+4*hi ----
  const int col = qc * 32 + l31;
  const float bv = bias[col];
  #pragma unroll
  for (int r = 0; r < 16; ++r) {
    const int orow = (r & 3) + 8 * (r >> 2) + 4 * hi;
    out[(size_t)(m0 + qr * 32 + orow) * N_DIM + col] = acc[r] + bv;
  }
}

extern "C" void kernel_launch(void* const* d_in, const int* in_sizes, int n_in,
                              void* d_out, int out_size, void* d_ws, size_t ws_size,
                              hipStream_t stream) {
  const float* x    = (const float*)d_in[0];
  const float* s    = (const float*)d_in[1];
  const float* a    = (const float*)d_in[2];
  const float* b    = (const float*)d_in[3];
  const float* bias = (const float*)d_in[4];
  float* out = (float*)d_out;
  unsigned short* wF = (unsigned short*)d_ws;   // 2*256*64*8*2B = 512 KB

  build_wF<<<1024, 256, 0, stream>>>(s, a, b, wF);
  kron_gemm<<<BATCH / ROWB, 256, 0, stream>>>(x, wF, bias, out);
}

// Round 6
// 140.200 us; speedup vs baseline: 1.0964x; 1.0964x over previous
//
#include <hip/hip_runtime.h>
#include <hip/hip_bf16.h>

#define RANK 16
#define BATCH 32768
#define K_DIM 4096   // A1*B1
#define N_DIM 64     // A2*B2
#define CHUNK 256    // K floats per chunk = 1KB per row (DRAM-page-friendly)
#define NCHUNK 16    // 4096/256
#define ROWB 32      // rows per block

typedef __bf16 bf16x8 __attribute__((ext_vector_type(8)));
typedef float floatx4 __attribute__((ext_vector_type(4)));
typedef unsigned short ushort8 __attribute__((ext_vector_type(8)));

#define WAITVM(n) asm volatile("s_waitcnt vmcnt(" #n ")" ::: "memory")
#define BARRIER() asm volatile("s_barrier" ::: "memory")

__device__ inline unsigned short f2bf(float f) {
  unsigned u = __builtin_bit_cast(unsigned, f);
  u += 0x7fffu + ((u >> 16) & 1u);   // round-to-nearest-even
  return (unsigned short)(u >> 16);
}

__device__ inline bf16x8 cvt8(float4 a0, float4 a1) {
  ushort8 au;
  au[0] = f2bf(a0.x); au[1] = f2bf(a0.y); au[2] = f2bf(a0.z); au[3] = f2bf(a0.w);
  au[4] = f2bf(a1.x); au[5] = f2bf(a1.y); au[6] = f2bf(a1.z); au[7] = f2bf(a1.w);
  return __builtin_bit_cast(bf16x8, au);
}

// Fragment-major w for the 16x16x32 B-operand: one dense 1KB slice per
// (col-group cg, K-step ks):
//   wF[((cg*128 + ks)*64 + lane)*8 + j] = w[k][n],
//   n = cg*16 + (lane&15), k = ks*32 + (lane>>4)*8 + j.
// Both the gemm's w-loads (16B/lane, lane-contiguous) and nothing else
// touch it -> dense, L2-resident.
__global__ __launch_bounds__(256) void build_wF(
    const float* __restrict__ s, const float* __restrict__ a,
    const float* __restrict__ b, unsigned short* __restrict__ wF) {
  int e = blockIdx.x * 256 + threadIdx.x;   // 0 .. 262143
  int j    = e & 7;
  int lane = (e >> 3) & 63;
  int ks   = (e >> 9) & 127;
  int cg   = e >> 16;
  int n = cg * 16 + (lane & 15);
  int k = ks * 32 + ((lane >> 4) << 3) + j;
  int i = k >> 6, kk = k & 63, jj = n >> 3, ll = n & 7;
  float acc = 0.f;
  #pragma unroll
  for (int r = 0; r < RANK; ++r) {
    acc += a[r * 512 + i * 8 + jj] * b[r * 512 + kk * 8 + ll];
  }
  acc *= s[i * 8 + jj];
  wF[e] = f2bf(acc);
}

// Block = 32 rows x 64 cols, 4 waves; wave = all 32 rows x 16 cols
// (2 frags of 16x16x32). x staged to LDS in 1KB-per-row contiguous
// global_load_lds instrs; w prefetched into REGISTERS one chunk ahead,
// issued BEFORE the gll ops of the same chunk so WAITVM(16) leaves
// exactly the next chunk's 16 vmem ops (8 w + 8 gll) in flight — the
// counted-vmcnt ring, with no vmem in the compute phase to drain it.
// A XOR-swizzle (16B-unit ^= row&7) applied on global source and on the
// ds_read side (both-sides rule); 64KB LDS -> 2 blocks/CU.
__global__ __launch_bounds__(256, 2) void kron_gemm(
    const float* __restrict__ x, const unsigned short* __restrict__ wF,
    const float* __restrict__ bias, float* __restrict__ out) {
  __shared__ __align__(16) float As[2][ROWB * CHUNK];   // 2 x 32 KB

  const int tid  = threadIdx.x;
  const int lane = tid & 63;
  const int wave = tid >> 6;     // = col-group cg
  const int ln15 = lane & 15;
  const int kseg = lane >> 4;
  const int m0   = blockIdx.x * ROWB;
  const int swl  = lane << 4;    // my 16B unit byte offset in a staged row

  floatx4 acc[2] = {};

  struct W8 { bf16x8 t[8]; };

  auto loadw = [&](int c) {
    W8 w;
    #pragma unroll
    for (int t = 0; t < 8; ++t)
      w.t[t] = *(const bf16x8*)(wF + (((size_t)(wave * 128 + c * 8 + t)) << 9)
                                + (lane << 3));
    return w;
  };

  auto stage = [&](float* buf, int c) {
    #pragma unroll
    for (int p = 0; p < 8; ++p) {
      const int row = wave * 8 + p;                       // wave-uniform
      const int sb  = swl ^ ((row & 7) << 4);             // swizzled src byte
      const float* src = x + (size_t)(m0 + row) * K_DIM + c * CHUNK + (sb >> 2);
      float* dst = buf + row * CHUNK;
      __builtin_amdgcn_global_load_lds(
          (const __attribute__((address_space(1))) void*)(const void*)src,
          (__attribute__((address_space(3))) void*)(void*)dst, 16, 0, 0);
    }
  };

  auto compute = [&](const float* buf, const W8& w) {
    const char* Ab = (const char*)buf;
    #pragma unroll
    for (int t = 0; t < 8; ++t) {
      #pragma unroll
      for (int f = 0; f < 2; ++f) {
        const int row = f * 16 + ln15;
        const int swz = (row & 7) << 4;
        const int b0  = t * 128 + kseg * 32;
        float4 lo = *(const float4*)(Ab + row * 1024 + ((b0)      ^ swz));
        float4 hi = *(const float4*)(Ab + row * 1024 + ((b0 + 16) ^ swz));
        acc[f] = __builtin_amdgcn_mfma_f32_16x16x32_bf16(cvt8(lo, hi), w.t[t],
                                                         acc[f], 0, 0, 0);
      }
    }
  };

  float* A0 = &As[0][0];
  float* A1 = &As[1][0];

  // ---- prologue: chunk 0 in flight ----
  W8 wA = loadw(0);
  stage(A0, 0);

  // ---- main loop: 2 chunks per iteration, static even/odd roles ----
  #pragma unroll 1
  for (int i = 0; i < 7; ++i) {
    const int c = 2 * i;
    W8 wB = loadw(c + 1);
    stage(A1, c + 1);
    WAITVM(16);            // chunk c landed; c+1's 16 ops stay in flight
    BARRIER();
    compute(A0, wA);
    BARRIER();             // all waves done reading A0

    wA = loadw(c + 2);
    stage(A0, c + 2);
    WAITVM(16);
    BARRIER();
    compute(A1, wB);
    BARRIER();
  }
  // ---- tail: chunks 14, 15 ----
  {
    W8 wB = loadw(15);
    stage(A1, 15);
    WAITVM(16);
    BARRIER();
    compute(A0, wA);
    BARRIER();
    WAITVM(0);
    BARRIER();
    compute(A1, wB);
  }

  // ---- epilogue: D col=lane&15, row=(lane>>4)*4+r (m89 mapping) ----
  const int col = wave * 16 + ln15;
  const float bv = bias[col];
  #pragma unroll
  for (int f = 0; f < 2; ++f) {
    float* op = out + (size_t)(m0 + f * 16 + kseg * 4) * N_DIM + col;
    #pragma unroll
    for (int r = 0; r < 4; ++r)
      op[(size_t)r * N_DIM] = acc[f][r] + bv;
  }
}

extern "C" void kernel_launch(void* const* d_in, const int* in_sizes, int n_in,
                              void* d_out, int out_size, void* d_ws, size_t ws_size,
                              hipStream_t stream) {
  const float* x    = (const float*)d_in[0];
  const float* s    = (const float*)d_in[1];
  const float* a    = (const float*)d_in[2];
  const float* b    = (const float*)d_in[3];
  const float* bias = (const float*)d_in[4];
  float* out = (float*)d_out;
  unsigned short* wF = (unsigned short*)d_ws;   // 512 KB

  build_wF<<<1024, 256, 0, stream>>>(s, a, b, wF);
  kron_gemm<<<BATCH / ROWB, 256, 0, stream>>>(x, wF, bias, out);
}

// Round 7
// 121.100 us; speedup vs baseline: 1.2693x; 1.1577x over previous
//
#include <hip/hip_runtime.h>
#include <hip/hip_bf16.h>

#define RANK 16
#define BATCH 32768
#define K_DIM 4096   // A1*B1
#define N_DIM 64     // A2*B2
#define CHUNK 128    // K floats per chunk = 512B per row
#define NCHUNK 32    // 4096/128
#define ROWB 64      // rows per block

typedef __bf16 bf16x8 __attribute__((ext_vector_type(8)));
typedef float floatx4 __attribute__((ext_vector_type(4)));
typedef unsigned short ushort8 __attribute__((ext_vector_type(8)));

#define WAITVM(n) asm volatile("s_waitcnt vmcnt(" #n ")" ::: "memory")
#define BARRIER() asm volatile("s_barrier" ::: "memory")

__device__ inline unsigned short f2bf(float f) {
  unsigned u = __builtin_bit_cast(unsigned, f);
  u += 0x7fffu + ((u >> 16) & 1u);   // round-to-nearest-even
  return (unsigned short)(u >> 16);
}

__device__ inline bf16x8 cvt8(float4 a0, float4 a1) {
  ushort8 au;
  au[0] = f2bf(a0.x); au[1] = f2bf(a0.y); au[2] = f2bf(a0.z); au[3] = f2bf(a0.w);
  au[4] = f2bf(a1.x); au[5] = f2bf(a1.y); au[6] = f2bf(a1.z); au[7] = f2bf(a1.w);
  return __builtin_bit_cast(bf16x8, au);
}

// Fragment-major w for the 16x16x32 B-operand (unchanged layout):
//   wF[((cg*128 + ks)*64 + lane)*8 + j] = w[k][n],
//   n = cg*16 + (lane&15), k = ks*32 + (lane>>4)*8 + j.
__global__ __launch_bounds__(256) void build_wF(
    const float* __restrict__ s, const float* __restrict__ a,
    const float* __restrict__ b, unsigned short* __restrict__ wF) {
  int e = blockIdx.x * 256 + threadIdx.x;   // 0 .. 262143
  int j    = e & 7;
  int lane = (e >> 3) & 63;
  int ks   = (e >> 9) & 127;
  int cg   = e >> 16;
  int n = cg * 16 + (lane & 15);
  int k = ks * 32 + ((lane >> 4) << 3) + j;
  int i = k >> 6, kk = k & 63, jj = n >> 3, ll = n & 7;
  float acc = 0.f;
  #pragma unroll
  for (int r = 0; r < RANK; ++r) {
    acc += a[r * 512 + i * 8 + jj] * b[r * 512 + kk * 8 + ll];
  }
  acc *= s[i * 8 + jj];
  wF[e] = f2bf(acc);
}

// Block = 64 rows x 64 cols, 4 waves; wave = ONE col-group (16 cols) x all
// 64 rows (4 A-frags). One w-fragment-load per K-step serves 4 row-frags,
// so per-block vmem bytes drop to x 1MB + w 512KB (vs 1MB+1MB effective
// at ROWB=32): the bottleneck identified in r6 is the per-CU vmem port
// rate (~13 B/cyc) carrying x(HBM)+w(L2) combined, so fewer total bytes
// per output is the lever. Counted-vmcnt ring as r6: w prefetched to
// registers BEFORE the gll stage ops of the same chunk; WAITVM(12)
// leaves exactly the next chunk's 12 vmem ops in flight; compute phase
// issues no vmem. XOR swizzle on global source + ds_read side.
__global__ __launch_bounds__(256, 2) void kron_gemm(
    const float* __restrict__ x, const unsigned short* __restrict__ wF,
    const float* __restrict__ bias, float* __restrict__ out) {
  __shared__ __align__(16) float As[2][ROWB * CHUNK];   // 2 x 32 KB

  const int tid  = threadIdx.x;
  const int lane = tid & 63;
  const int wave = tid >> 6;     // = col-group cg
  const int ln15 = lane & 15;
  const int kseg = lane >> 4;
  const int m0   = blockIdx.x * ROWB;
  const int rhalf = lane >> 5;   // staging: row within the 1KB pair

  floatx4 acc[4] = {};

  struct W4 { bf16x8 t[4]; };

  auto loadw = [&](int c) {
    W4 w;
    #pragma unroll
    for (int t = 0; t < 4; ++t)
      w.t[t] = *(const bf16x8*)(wF + (((size_t)(wave * 128 + c * 4 + t)) << 9)
                                + (lane << 3));
    return w;
  };

  // stage chunk c: 8 gll instrs/wave, each 1KB = 2 rows x 512B
  auto stage = [&](float* buf, int c) {
    #pragma unroll
    for (int p = 0; p < 8; ++p) {
      const int rbase = wave * 16 + 2 * p;               // wave-uniform
      const int row   = rbase + rhalf;                   // per-lane
      const int sb    = ((lane & 31) << 4) ^ ((row & 7) << 4);
      const float* src = x + (size_t)(m0 + row) * K_DIM + c * CHUNK + (sb >> 2);
      float* dst = buf + rbase * CHUNK;
      __builtin_amdgcn_global_load_lds(
          (const __attribute__((address_space(1))) void*)(const void*)src,
          (__attribute__((address_space(3))) void*)(void*)dst, 16, 0, 0);
    }
  };

  auto compute = [&](const float* buf, const W4& w) {
    const char* Ab = (const char*)buf;
    #pragma unroll
    for (int t = 0; t < 4; ++t) {
      #pragma unroll
      for (int f = 0; f < 4; ++f) {
        const int row = f * 16 + ln15;
        const int swz = (row & 7) << 4;
        const int b0  = t * 128 + kseg * 32;
        float4 lo = *(const float4*)(Ab + row * 512 + ((b0)      ^ swz));
        float4 hi = *(const float4*)(Ab + row * 512 + ((b0 + 16) ^ swz));
        acc[f] = __builtin_amdgcn_mfma_f32_16x16x32_bf16(cvt8(lo, hi), w.t[t],
                                                         acc[f], 0, 0, 0);
      }
    }
  };

  float* A0 = &As[0][0];
  float* A1 = &As[1][0];

  // ---- prologue: chunk 0 in flight ----
  W4 wA = loadw(0);
  stage(A0, 0);

  // ---- main loop: 2 chunks per iteration, static even/odd roles ----
  #pragma unroll 1
  for (int i = 0; i < 15; ++i) {
    const int c = 2 * i;
    W4 wB = loadw(c + 1);
    stage(A1, c + 1);
    WAITVM(12);            // chunk c landed; c+1's 12 ops stay in flight
    BARRIER();
    compute(A0, wA);
    BARRIER();             // all waves done reading A0

    wA = loadw(c + 2);
    stage(A0, c + 2);
    WAITVM(12);
    BARRIER();
    compute(A1, wB);
    BARRIER();
  }
  // ---- tail: chunks 30, 31 ----
  {
    W4 wB = loadw(31);
    stage(A1, 31);
    WAITVM(12);
    BARRIER();
    compute(A0, wA);
    BARRIER();
    WAITVM(0);
    BARRIER();
    compute(A1, wB);
  }

  // ---- epilogue: D col=lane&15, row=(lane>>4)*4+r (m89 mapping) ----
  const int col = wave * 16 + ln15;
  const float bv = bias[col];
  #pragma unroll
  for (int f = 0; f < 4; ++f) {
    float* op = out + (size_t)(m0 + f * 16 + kseg * 4) * N_DIM + col;
    #pragma unroll
    for (int r = 0; r < 4; ++r)
      op[(size_t)r * N_DIM] = acc[f][r] + bv;
  }
}

extern "C" void kernel_launch(void* const* d_in, const int* in_sizes, int n_in,
                              void* d_out, int out_size, void* d_ws, size_t ws_size,
                              hipStream_t stream) {
  const float* x    = (const float*)d_in[0];
  const float* s    = (const float*)d_in[1];
  const float* a    = (const float*)d_in[2];
  const float* b    = (const float*)d_in[3];
  const float* bias = (const float*)d_in[4];
  float* out = (float*)d_out;
  unsigned short* wF = (unsigned short*)d_ws;   // 512 KB

  build_wF<<<1024, 256, 0, stream>>>(s, a, b, wF);
  kron_gemm<<<BATCH / ROWB, 256, 0, stream>>>(x, wF, bias, out);
}